// Round 5
// baseline (107.418 us; speedup 1.0000x reference)
//
#include <hip/hip_runtime.h>
#include <hip/hip_bf16.h>
#include <cstdint>
#include <cstddef>

// Problem dims (fixed): B=4, NI=NO=256, DIN=DQ=DH=DOUT=256.
// out[b,i,j,:] = gelu(u[b,i,:] + v[b,j,:]) @ W2 + b2
//   u = (x@W_pre + b_pre)@W1[:256] + b1   (b1 folded into u)
//   v = (query@W_emb + b_emb)@W1[256:]

typedef __bf16  bf16x8 __attribute__((ext_vector_type(8)));
typedef float   f32x16 __attribute__((ext_vector_type(16)));

// tanh-approx gelu with exp2 constant pre-folded:
// gelu(x) ~= x / (1 + exp2(x*(-2.3022072 - 0.1029433*x^2)))
__device__ __forceinline__ float fast_gelu(float x) {
    const float x2 = x * x;
    const float m  = __builtin_fmaf(x2, -0.1029433f, -2.3022072f);
    const float e  = __builtin_amdgcn_exp2f(x * m);
    return x * __builtin_amdgcn_rcpf(1.0f + e);
}

// ---------------------------------------------------------------------------
// Prep kernel (one launch):
//   blocks [0,256):   u rows — x path (4 rows/block)
//   blocks [256,512): v rows — query path
//   blocks [512,576): W2T[n][k] = bf16(W2[k][n])  (4 n-cols/block)
// ---------------------------------------------------------------------------
__global__ __launch_bounds__(256) void prep_kernel(
    const float* __restrict__ x, const float* __restrict__ query,
    const float* __restrict__ W_pre, const float* __restrict__ b_pre,
    const float* __restrict__ W_emb, const float* __restrict__ b_emb,
    const float* __restrict__ W1, const float* __restrict__ b1,
    const float* __restrict__ W2,
    float* __restrict__ u, float* __restrict__ v,
    unsigned short* __restrict__ w2t)
{
    const int b = blockIdx.x;
    const int t = threadIdx.x;

    if (b >= 512) {                       // W2 transpose + bf16 convert
        const int n0 = (b - 512) * 4;
        const float4 wv = *reinterpret_cast<const float4*>(W2 + (size_t)t * 256 + n0);
        const float vals[4] = {wv.x, wv.y, wv.z, wv.w};
#pragma unroll
        for (int j = 0; j < 4; ++j) {
            const __bf16 bv = (__bf16)vals[j];
            w2t[(size_t)(n0 + j) * 256 + t] = __builtin_bit_cast(unsigned short, bv);
        }
        return;
    }

    const bool isq = (b >= 256);
    const float* __restrict__ A   = isq ? query : x;
    const float* __restrict__ Wa  = isq ? W_emb : W_pre;
    const float* __restrict__ ba  = isq ? b_emb : b_pre;
    const float* __restrict__ W1p = isq ? (W1 + 256 * 256) : W1;
    float* __restrict__ outp      = isq ? v : u;
    const int r0 = (isq ? (b - 256) : b) * 4;

    __shared__ float as[4][256];
    __shared__ float xs[4][256];

#pragma unroll
    for (int r = 0; r < 4; ++r)
        as[r][t] = A[(size_t)(r0 + r) * 256 + t];
    __syncthreads();

    float acc[4] = {0.f, 0.f, 0.f, 0.f};
    for (int k = 0; k < 256; ++k) {
        const float wv = Wa[(size_t)k * 256 + t];
#pragma unroll
        for (int r = 0; r < 4; ++r) acc[r] += as[r][k] * wv;
    }
    const float bav = ba[t];
#pragma unroll
    for (int r = 0; r < 4; ++r) xs[r][t] = acc[r] + bav;
    __syncthreads();

    float acc2[4] = {0.f, 0.f, 0.f, 0.f};
    for (int k = 0; k < 256; ++k) {
        const float wv = W1p[(size_t)k * 256 + t];
#pragma unroll
        for (int r = 0; r < 4; ++r) acc2[r] += xs[r][k] * wv;
    }
    const float b1v = isq ? 0.f : b1[t];
#pragma unroll
    for (int r = 0; r < 4; ++r)
        outp[(size_t)(r0 + r) * 256 + t] = acc2[r] + b1v;
}

// ---------------------------------------------------------------------------
// Fused main kernel (T3 minimum-2-phase pipeline, 1 barrier per k-chunk).
// Block = 512 threads = 8 waves; tile = 256 output rows (one (b,i); all j)
// x 256 cols. 1024 blocks total. Wave grid 4x2: wave w -> (wr=w>>1, wc=w&1)
// owns 64 rows x 128 cols -> acc 2x4 f32x16 = 128 VGPR.
//
// LDS (128 KB, double-buffered):
//   wlds[2]: W2T chunk [256 n][64 k] bf16, XOR-swizzled granules (32 KB ea)
//   hlds[2]: H tile    [256 r][64 k] bf16, XOR-swizzled granules (32 KB ea)
//
// Per chunk c: { issue async gll W2T[c+1] + V-loads[c+1] -> regs;
//                MFMA on buffers[c]; gelu(V[c+1]) -> ds_write H[c+1];
//                __syncthreads (single barrier: drains gll + ds_writes) }
// gll/V-load latency hides under MFMA+gelu of the current chunk.
//
// mfma_f32_32x32x16_bf16 layouts (gfx950):
//   A: lane l holds A[l&31][(l>>5)*8 + e]
//   B: lane l holds B[(l>>5)*8 + e][l&31]
//   D: lane l reg r holds D[(r&3) + 8*(r>>2) + 4*(l>>5)][l&31]
// ---------------------------------------------------------------------------
__global__ __launch_bounds__(512, 2) void fused_kernel(
    const float* __restrict__ U, const float* __restrict__ V,
    const unsigned short* __restrict__ W2T, const float* __restrict__ b2,
    float* __restrict__ out)
{
    __shared__ uint4 wlds[2][2048];   // 2 x 32 KB
    __shared__ uint4 hlds[2][2048];   // 2 x 32 KB

    const int t    = threadIdx.x;
    const int lane = t & 63;
    const int w    = t >> 6;          // 0..7
    const int l31  = lane & 31;
    const int hi   = lane >> 5;       // 0..1
    const int wr   = w >> 1;          // 0..3 row-quad
    const int wc   = w & 1;           // 0..1 col-half

    const int bid = blockIdx.x;
    const int bb  = bid >> 8;
    const int ii  = bid & 255;
    const size_t r0 = (size_t)bid * 256;

    const float* __restrict__ urow  = U + ((size_t)(bb * 256 + ii)) * 256;
    const float* __restrict__ vbase = V + ((size_t)bb * 256) * 256;

    // H-compute mapping: thread -> (k-dword d, row-base rb); 16 rows/pass.
    const int d  = t & 31;            // k-pair index: k = kk + 2d, 2d+1
    const int rb = t >> 5;            // 0..15

    f32x16 acc[2][4];
#pragma unroll
    for (int rg = 0; rg < 2; ++rg)
#pragma unroll
        for (int cg = 0; cg < 4; ++cg) acc[rg][cg] = (f32x16)0.f;

    float2 vv[16];
    float2 u2;

    auto stage_w2t = [&](int kk, int buf) {
#pragma unroll
        for (int it = 0; it < 4; ++it) {
            const int idx = it * 512 + t;    // linear granule in LDS
            const int n   = idx >> 3;        // 0..255
            const int gp  = idx & 7;         // LDS granule slot
            const int g   = gp ^ (n & 7);    // inverse-swizzled source granule
            __builtin_amdgcn_global_load_lds(
                (const __attribute__((address_space(1))) unsigned int*)
                    (W2T + (size_t)n * 256 + kk + g * 8),
                (__attribute__((address_space(3))) unsigned int*)
                    (&wlds[buf][idx]),
                16, 0, 0);
        }
    };

    auto load_v = [&](int kk) {
        u2 = *reinterpret_cast<const float2*>(urow + kk + 2 * d);
#pragma unroll
        for (int p = 0; p < 16; ++p) {
            const int row = rb + p * 16;     // 2 whole rows per wave-instr
            vv[p] = *reinterpret_cast<const float2*>(
                vbase + (size_t)row * 256 + kk + 2 * d);
        }
    };

    auto gelu_write = [&](int buf) {
        unsigned int* h32 = reinterpret_cast<unsigned int*>(&hlds[buf][0]);
#pragma unroll
        for (int p = 0; p < 16; ++p) {
            const int row = rb + p * 16;
            union { unsigned int u32; __bf16 h[2]; } pk;
            pk.h[0] = (__bf16)fast_gelu(u2.x + vv[p].x);
            pk.h[1] = (__bf16)fast_gelu(u2.y + vv[p].y);
            h32[row * 32 + (((d >> 2) ^ (row & 7)) << 2) + (d & 3)] = pk.u32;
        }
    };

    auto mfma_phase = [&](int buf) {
#pragma unroll
        for (int s = 0; s < 4; ++s) {
            const int gk = 2 * s + hi;       // k-granule within chunk
            bf16x8 af[2];
#pragma unroll
            for (int rg = 0; rg < 2; ++rg) {
                const int arow = wr * 64 + rg * 32 + l31;
                af[rg] = __builtin_bit_cast(
                    bf16x8, hlds[buf][arow * 8 + (gk ^ (arow & 7))]);
            }
#pragma unroll
            for (int cg = 0; cg < 4; ++cg) {
                const int col = wc * 128 + cg * 32 + l31;
                const bf16x8 bf_ = __builtin_bit_cast(
                    bf16x8, wlds[buf][col * 8 + (gk ^ (col & 7))]);
#pragma unroll
                for (int rg = 0; rg < 2; ++rg)
                    acc[rg][cg] = __builtin_amdgcn_mfma_f32_32x32x16_bf16(
                        af[rg], bf_, acc[rg][cg], 0, 0, 0);
            }
        }
    };

    // ---- prologue: fill buffer 0 ----
    stage_w2t(0, 0);
    load_v(0);
    gelu_write(0);
    __syncthreads();

    // ---- main loop: one barrier per chunk ----
#pragma unroll
    for (int c = 0; c < 4; ++c) {
        if (c < 3) {
            stage_w2t((c + 1) * 64, (c + 1) & 1);
            load_v((c + 1) * 64);
        }
        mfma_phase(c & 1);
        if (c < 3) gelu_write((c + 1) & 1);
        __syncthreads();
    }

    // ---- epilogue: out[row][col] = acc + b2[col], nontemporal ----
#pragma unroll
    for (int rg = 0; rg < 2; ++rg) {
#pragma unroll
        for (int cg = 0; cg < 4; ++cg) {
            const int col = wc * 128 + cg * 32 + l31;
            const float bv = b2[col];
#pragma unroll
            for (int rr = 0; rr < 16; ++rr) {
                const int row = wr * 64 + rg * 32 + 4 * hi + (rr & 3) + 8 * (rr >> 2);
                __builtin_nontemporal_store(acc[rg][cg][rr] + bv,
                                            out + (r0 + row) * 256 + col);
            }
        }
    }
}

// ---------------------------------------------------------------------------
extern "C" void kernel_launch(void* const* d_in, const int* in_sizes, int n_in,
                              void* d_out, int out_size, void* d_ws, size_t ws_size,
                              hipStream_t stream)
{
    const float* x     = (const float*)d_in[0];
    const float* query = (const float*)d_in[1];
    const float* W_pre = (const float*)d_in[2];
    const float* b_pre = (const float*)d_in[3];
    const float* W_emb = (const float*)d_in[4];
    const float* b_emb = (const float*)d_in[5];
    const float* W1    = (const float*)d_in[6];
    const float* b1    = (const float*)d_in[7];
    const float* W2    = (const float*)d_in[8];
    const float* b2    = (const float*)d_in[9];
    float* out = (float*)d_out;

    char* ws = (char*)d_ws;
    float* u            = (float*)(ws);                          // 1 MB
    float* v            = (float*)(ws + (1 << 20));              // 1 MB
    unsigned short* w2t = (unsigned short*)(ws + 2 * (1 << 20)); // 128 KB

    prep_kernel<<<576, 256, 0, stream>>>(x, query, W_pre, b_pre, W_emb, b_emb,
                                         W1, b1, W2, u, v, w2t);
    fused_kernel<<<1024, 512, 0, stream>>>(u, v, w2t, b2, out);
}